// Round 3
// baseline (985.204 us; speedup 1.0000x reference)
//
#include <hip/hip_runtime.h>
#include <cstddef>

typedef unsigned short u16;
typedef __attribute__((ext_vector_type(8))) short bf16x8;
typedef __attribute__((ext_vector_type(4))) float f32x4;

constexpr int nB = 8, nC = 256, nN = 768, nT = 12, nM = nN * nT, nH = 64;
constexpr int nMtot = nB * nM;   // 73728
constexpr float SCALE = 0.125f;
constexpr float LNEPS = 1e-6f;

// ---------------- bf16 helpers ----------------
__device__ inline u16 f2b(float f) {
    union { float f; unsigned u; } v; v.f = f;
    unsigned r = v.u + 0x7FFFu + ((v.u >> 16) & 1u);
    return (u16)(r >> 16);
}
__device__ inline float b2f(u16 h) {
    union { unsigned u; float f; } v; v.u = ((unsigned)h) << 16;
    return v.f;
}
__device__ inline uint2 packb4(float a, float b, float c, float d) {
    uint2 r;
    r.x = (unsigned)f2b(a) | ((unsigned)f2b(b) << 16);
    r.y = (unsigned)f2b(c) | ((unsigned)f2b(d) << 16);
    return r;
}
__device__ inline f32x4 mfma16(bf16x8 a, bf16x8 b, f32x4 c) {
    return __builtin_amdgcn_mfma_f32_16x16x32_bf16(a, b, c, 0, 0, 0);
}

// Stage a 64x64 bf16 tile (row stride ld elements) into LDS [64][72].
__device__ inline void stage64(const u16* __restrict__ g, int ld, u16* lds, int tid) {
#pragma unroll
    for (int r = 0; r < 2; ++r) {
        int c = tid + r * 256;
        int row = c >> 3, kc = (c & 7) * 8;
        *(uint4*)&lds[row * 72 + kc] = *(const uint4*)&g[(size_t)row * ld + kc];
    }
}

// One 64-wide K-chunk of MFMA compute over a 64x64 tile (4 waves, 32x32/wave).
__device__ inline void mfma_block(const u16* As, const u16* Bs, f32x4 acc[2][2],
                                  int wo, int wm, int quad, int r) {
#pragma unroll
    for (int ks = 0; ks < 64; ks += 32) {
        bf16x8 a0 = *(const bf16x8*)&As[(wo + r) * 72 + ks + quad * 8];
        bf16x8 a1 = *(const bf16x8*)&As[(wo + 16 + r) * 72 + ks + quad * 8];
        bf16x8 b0 = *(const bf16x8*)&Bs[(wm + r) * 72 + ks + quad * 8];
        bf16x8 b1 = *(const bf16x8*)&Bs[(wm + 16 + r) * 72 + ks + quad * 8];
        acc[0][0] = mfma16(a0, b0, acc[0][0]);
        acc[0][1] = mfma16(a0, b1, acc[0][1]);
        acc[1][0] = mfma16(a1, b0, acc[1][0]);
        acc[1][1] = mfma16(a1, b1, acc[1][1]);
    }
}

// ---------------- weight conversion (fp32 -> bf16, with q/k transposes) ------
__global__ __launch_bounds__(256) void cvt_w(const float* __restrict__ Wnq,
                                             const float* __restrict__ Wnk,
                                             const float* __restrict__ Wtq,
                                             const float* __restrict__ Wtk,
                                             const float* __restrict__ vw,
                                             const float* __restrict__ fcvw,
                                             const float* __restrict__ projw,
                                             const float* __restrict__ w1,
                                             const float* __restrict__ w2,
                                             u16* __restrict__ WB) {
    int i = blockIdx.x * 256 + threadIdx.x;
    float v;
    if (i < 65536) {
        int seg = i >> 14, j = i & 16383;
        int o = j >> 8, k = j & 255;
        const float* src = seg == 0 ? Wnq : seg == 1 ? Wnk : seg == 2 ? Wtq : Wtk;
        v = src[k * 64 + o];                       // [c][h] -> [h][c]
    } else if (i < 81920)  v = vw[i - 65536];
    else if (i < 114688)   v = fcvw[i - 81920];
    else if (i < 147456)   v = projw[i - 114688];
    else if (i < 409600)   v = w1[i - 147456];
    else                   v = w2[i - 409600];
    WB[i] = f2b(v);
}

__global__ __launch_bounds__(256) void zero_f(float* __restrict__ p) {
    p[blockIdx.x * 256 + threadIdx.x] = 0.f;
}

// ---------------- LayerNorm (channels-first fp32 in, channels-last bf16 out) --
__global__ __launch_bounds__(256) void ln_cl(const float* __restrict__ X,
                                             const float* __restrict__ w,
                                             const float* __restrict__ bias,
                                             u16* __restrict__ Y) {
    int tid = threadIdx.x;
    int lane = tid & 63, cg = tid >> 6;
    int m0 = blockIdx.x * 64, b = blockIdx.y;
    size_t base = (size_t)b * nC * nM + m0 + lane;
    float s = 0.f, ss = 0.f;
#pragma unroll 4
    for (int k = 0; k < 64; ++k) {
        float v = X[base + (size_t)(cg * 64 + k) * nM];
        s += v; ss += v * v;
    }
    __shared__ float rs[4][64], rss[4][64], mu_s[64], rstd_s[64];
    __shared__ u16 Lo[64][264];
    rs[cg][lane] = s; rss[cg][lane] = ss;
    __syncthreads();
    if (tid < 64) {
        float t1 = rs[0][lane] + rs[1][lane] + rs[2][lane] + rs[3][lane];
        float t2 = rss[0][lane] + rss[1][lane] + rss[2][lane] + rss[3][lane];
        float mu = t1 * (1.f / nC);
        float var = t2 * (1.f / nC) - mu * mu;
        mu_s[lane] = mu;
        rstd_s[lane] = rsqrtf(var + LNEPS);
    }
    __syncthreads();
    float mu = mu_s[lane], rstd = rstd_s[lane];
#pragma unroll 8
    for (int k = 0; k < 64; k += 2) {
        int c = cg * 64 + k;
        float v0 = (X[base + (size_t)c * nM] - mu) * rstd * w[c] + bias[c];
        float v1 = (X[base + (size_t)(c + 1) * nM] - mu) * rstd * w[c + 1] + bias[c + 1];
        *(unsigned*)&Lo[lane][c] = (unsigned)f2b(v0) | ((unsigned)f2b(v1) << 16);
    }
    __syncthreads();
#pragma unroll
    for (int r = 0; r < 8; ++r) {
        int c = tid + r * 256;
        int mm = c >> 5, ch = (c & 31) * 8;
        *(uint4*)&Y[((size_t)b * nM + m0 + mm) * 256 + ch] = *(uint4*)&Lo[mm][ch];
    }
}

// ---------------- v1 projection (output [bt][64][nN], 64x64 tile) -----------
__global__ __launch_bounds__(256) void gemm_v1(const u16* __restrict__ X,
                                               const u16* __restrict__ W,
                                               const float* __restrict__ bias,
                                               u16* __restrict__ OUT) {
    __shared__ u16 As[64 * 72], Bs[64 * 72];
    int tid = threadIdx.x;
    int m0 = blockIdx.x * 64, b = blockIdx.y;
    int lane = tid & 63, wid = tid >> 6;
    int wo = (wid & 1) * 32, wm = (wid >> 1) * 32;
    int quad = lane >> 4, r = lane & 15;
    const u16* Ag = W;
    const u16* Bg = X + ((size_t)b * nM + m0) * 256;
    f32x4 acc[2][2] = {};
    for (int k0 = 0; k0 < 256; k0 += 64) {
        __syncthreads();
        stage64(Ag + k0, 256, As, tid);
        stage64(Bg + k0, 256, Bs, tid);
        __syncthreads();
        mfma_block(As, Bs, acc, wo, wm, quad, r);
    }
#pragma unroll
    for (int oi = 0; oi < 2; ++oi)
#pragma unroll
        for (int mj = 0; mj < 2; ++mj) {
            int o = wo + oi * 16 + quad * 4;
            int m = m0 + wm + mj * 16 + r;
            int n = m / 12, t = m - n * 12;
            size_t bt = (size_t)(b * 12 + t) * 64;
            f32x4 a = acc[oi][mj];
            OUT[(bt + o) * nN + n]     = f2b(a[0] + bias[o]);
            OUT[(bt + o + 1) * nN + n] = f2b(a[1] + bias[o + 1]);
            OUT[(bt + o + 2) * nN + n] = f2b(a[2] + bias[o + 2]);
            OUT[(bt + o + 3) * nN + n] = f2b(a[3] + bias[o + 3]);
        }
}

// ---------------- dual 128m x 64o GEMM (shared X read, two weight sets) ------
// MODE 0: nq/nk -> [bt][n][64] layout.  MODE 1: tq/tk -> [m][64] layout.
// MODE 2: ffn1 gated: out = (A+ba)*gelu(G+bb) -> [m][512] at col o0+o.
template <int MODE>
__global__ __launch_bounds__(256) void dual64(const u16* __restrict__ X,
                                              const u16* __restrict__ Wa,
                                              const u16* __restrict__ Wb,
                                              const float* __restrict__ ba,
                                              const float* __restrict__ bb,
                                              u16* __restrict__ OA,
                                              u16* __restrict__ OB,
                                              int K) {
    __shared__ u16 Was[64 * 72], Wbs[64 * 72], Xs[128 * 72];
    int tid = threadIdx.x;
    int m0 = blockIdx.x * 128, o0 = blockIdx.y * 64;
    int lane = tid & 63, wid = tid >> 6;
    int wo = (wid & 1) * 32, wm = (wid >> 1) * 64;
    int quad = lane >> 4, r = lane & 15;
    const u16* WaP = Wa + (size_t)o0 * K;
    const u16* WbP = Wb + (size_t)o0 * K;
    f32x4 accA[2][4] = {}, accB[2][4] = {};
    for (int k0 = 0; k0 < K; k0 += 64) {
        __syncthreads();
#pragma unroll
        for (int it = 0; it < 2; ++it) {
            int idx = tid + it * 256;
            int row = idx >> 3, c8 = (idx & 7) * 8;
            *(uint4*)&Was[row * 72 + c8] = *(const uint4*)&WaP[(size_t)row * K + k0 + c8];
            *(uint4*)&Wbs[row * 72 + c8] = *(const uint4*)&WbP[(size_t)row * K + k0 + c8];
        }
#pragma unroll
        for (int it = 0; it < 4; ++it) {
            int idx = tid + it * 256;
            int row = idx >> 3, c8 = (idx & 7) * 8;
            *(uint4*)&Xs[row * 72 + c8] = *(const uint4*)&X[(size_t)(m0 + row) * K + k0 + c8];
        }
        __syncthreads();
#pragma unroll
        for (int ks = 0; ks < 64; ks += 32) {
            bf16x8 aA[2], aB[2], bx[4];
#pragma unroll
            for (int i = 0; i < 2; ++i) {
                aA[i] = *(const bf16x8*)&Was[(wo + i * 16 + r) * 72 + ks + quad * 8];
                aB[i] = *(const bf16x8*)&Wbs[(wo + i * 16 + r) * 72 + ks + quad * 8];
            }
#pragma unroll
            for (int j = 0; j < 4; ++j)
                bx[j] = *(const bf16x8*)&Xs[(wm + j * 16 + r) * 72 + ks + quad * 8];
#pragma unroll
            for (int i = 0; i < 2; ++i)
#pragma unroll
                for (int j = 0; j < 4; ++j) {
                    accA[i][j] = mfma16(aA[i], bx[j], accA[i][j]);
                    accB[i][j] = mfma16(aB[i], bx[j], accB[i][j]);
                }
        }
    }
#pragma unroll
    for (int i = 0; i < 2; ++i)
#pragma unroll
        for (int j = 0; j < 4; ++j) {
            int o = o0 + wo + i * 16 + quad * 4;
            int m = m0 + wm + j * 16 + r;
            f32x4 a = accA[i][j], g = accB[i][j];
            if (MODE == 2) {
                float vals[4];
#pragma unroll
                for (int rr = 0; rr < 4; ++rr) {
                    float aa = a[rr] + ba[o + rr];
                    float gg = g[rr] + bb[o + rr];
                    float gl = 0.5f * gg * (1.f + erff(gg * 0.70710678118654752f));
                    vals[rr] = aa * gl;
                }
                *(uint2*)&OA[(size_t)m * 512 + o] = packb4(vals[0], vals[1], vals[2], vals[3]);
            } else {
                size_t row;
                if (MODE == 0) {
                    int b = m / nM, mm = m - b * nM;
                    int n = mm / 12, t = mm - n * 12;
                    row = (size_t)(b * 12 + t) * nN + n;
                } else {
                    row = (size_t)m;
                }
                *(uint2*)&OA[row * 64 + o] =
                    packb4(a[0] + ba[o], a[1] + ba[o + 1], a[2] + ba[o + 2], a[3] + ba[o + 3]);
                *(uint2*)&OB[row * 64 + o] =
                    packb4(g[0] + bb[o], g[1] + bb[o + 1], g[2] + bb[o + 2], g[3] + bb[o + 3]);
            }
        }
}

// ---------------- big 128x128 GEMM: A=W[O][K], B=X[Mtot][K] ------------------
// EPI 0: bf16 channels-last OUT[m][O].  EPI 1: fp32 channels-first + residual.
// PROD: B-tile is elementwise product of B and B2.
template <int EPI, bool PROD>
__global__ __launch_bounds__(256) void gemm128(const u16* __restrict__ A,
                                               const u16* __restrict__ B,
                                               const u16* __restrict__ B2,
                                               const float* __restrict__ bias,
                                               const float* __restrict__ RES,
                                               void* __restrict__ OUTv,
                                               int K, int O) {
    __shared__ u16 As[128 * 72], Bs[128 * 72];
    int tid = threadIdx.x;
    int m0 = blockIdx.x * 128, o0 = blockIdx.y * 128;
    int lane = tid & 63, wid = tid >> 6;
    int wo = (wid & 1) * 64, wm = (wid >> 1) * 64;
    int quad = lane >> 4, r = lane & 15;
    f32x4 acc[4][4] = {};
    for (int k0 = 0; k0 < K; k0 += 64) {
        __syncthreads();
#pragma unroll
        for (int it = 0; it < 4; ++it) {
            int idx = tid + it * 256;
            int row = idx >> 3, c8 = (idx & 7) * 8;
            *(uint4*)&As[row * 72 + c8] = *(const uint4*)&A[(size_t)(o0 + row) * K + k0 + c8];
        }
#pragma unroll
        for (int it = 0; it < 4; ++it) {
            int idx = tid + it * 256;
            int row = idx >> 3, c8 = (idx & 7) * 8;
            size_t gi = (size_t)(m0 + row) * K + k0 + c8;
            if (!PROD) {
                *(uint4*)&Bs[row * 72 + c8] = *(const uint4*)&B[gi];
            } else {
                uint4 hv = *(const uint4*)&B[gi];
                uint4 vv = *(const uint4*)&B2[gi];
                u16* hs = (u16*)&hv; u16* vs = (u16*)&vv;
                union { uint4 q; u16 s[8]; } ov;
#pragma unroll
                for (int q2 = 0; q2 < 8; ++q2) ov.s[q2] = f2b(b2f(hs[q2]) * b2f(vs[q2]));
                *(uint4*)&Bs[row * 72 + c8] = ov.q;
            }
        }
        __syncthreads();
#pragma unroll
        for (int ks = 0; ks < 64; ks += 32) {
            bf16x8 av[4], bv[4];
#pragma unroll
            for (int i = 0; i < 4; ++i)
                av[i] = *(const bf16x8*)&As[(wo + i * 16 + r) * 72 + ks + quad * 8];
#pragma unroll
            for (int j = 0; j < 4; ++j)
                bv[j] = *(const bf16x8*)&Bs[(wm + j * 16 + r) * 72 + ks + quad * 8];
#pragma unroll
            for (int i = 0; i < 4; ++i)
#pragma unroll
                for (int j = 0; j < 4; ++j)
                    acc[i][j] = mfma16(av[i], bv[j], acc[i][j]);
        }
    }
#pragma unroll
    for (int i = 0; i < 4; ++i)
#pragma unroll
        for (int j = 0; j < 4; ++j) {
            int o = o0 + wo + i * 16 + quad * 4;
            int m = m0 + wm + j * 16 + r;
            f32x4 a = acc[i][j];
            if (EPI == 0) {
                u16* OUT = (u16*)OUTv;
                *(uint2*)&OUT[(size_t)m * O + o] =
                    packb4(a[0] + bias[o], a[1] + bias[o + 1],
                           a[2] + bias[o + 2], a[3] + bias[o + 3]);
            } else {
                float* OUT = (float*)OUTv;
                int b = m / nM, mm = m - b * nM;
                size_t idx = ((size_t)b * O + o) * nM + mm;
#pragma unroll
                for (int rr = 0; rr < 4; ++rr)
                    OUT[idx + (size_t)rr * nM] =
                        a[rr] + bias[o + rr] + RES[idx + (size_t)rr * nM];
            }
        }
}

// ---------------- node scores: SE = exp(scale*qk + Bn), + row sums ----------
__global__ __launch_bounds__(256) void scores_k(const u16* __restrict__ NQ,
                                                const u16* __restrict__ NK,
                                                const float* __restrict__ Bn,
                                                u16* __restrict__ SE,
                                                float* __restrict__ rowsum) {
    __shared__ u16 As[64 * 72], Bs[64 * 72];
    __shared__ float lsum[64];
    int tid = threadIdx.x;
    int j0 = blockIdx.x * 64, i0 = blockIdx.y * 64, bt = blockIdx.z;
    if (tid < 64) lsum[tid] = 0.f;
    int lane = tid & 63, wid = tid >> 6;
    int wo = (wid & 1) * 32, wm = (wid >> 1) * 32;
    int quad = lane >> 4, r = lane & 15;
    const u16* Ag = NQ + ((size_t)bt * nN + i0) * 64;
    const u16* Bg = NK + ((size_t)bt * nN + j0) * 64;
    f32x4 acc[2][2] = {};
    __syncthreads();
    stage64(Ag, 64, As, tid);
    stage64(Bg, 64, Bs, tid);
    __syncthreads();
    mfma_block(As, Bs, acc, wo, wm, quad, r);
#pragma unroll
    for (int oi = 0; oi < 2; ++oi) {
        f32x4 rsm = {0.f, 0.f, 0.f, 0.f};
#pragma unroll
        for (int mj = 0; mj < 2; ++mj) {
            int i_ = i0 + wo + oi * 16 + quad * 4;
            int j_ = j0 + wm + mj * 16 + r;
#pragma unroll
            for (int rr = 0; rr < 4; ++rr) {
                float s = acc[oi][mj][rr] * SCALE + Bn[(size_t)(i_ + rr) * nN + j_];
                float e = expf(s);
                SE[((size_t)bt * nN + i_ + rr) * nN + j_] = f2b(e);
                rsm[rr] += e;
            }
        }
#pragma unroll
        for (int mask = 1; mask < 16; mask <<= 1) {
            rsm[0] += __shfl_xor(rsm[0], mask);
            rsm[1] += __shfl_xor(rsm[1], mask);
            rsm[2] += __shfl_xor(rsm[2], mask);
            rsm[3] += __shfl_xor(rsm[3], mask);
        }
        if (r == 0) {
#pragma unroll
            for (int rr = 0; rr < 4; ++rr)
                atomicAdd(&lsum[wo + oi * 16 + quad * 4 + rr], rsm[rr]);
        }
    }
    __syncthreads();
    if (tid < 64) atomicAdd(&rowsum[(size_t)bt * nN + i0 + tid], lsum[tid]);
}

// ---------------- node aggregation fused with attn finalize ------------------
// hs[c][w] = sum_v v1n[c][v] * (SE[v][w]*adj[v][w]/rowsum[v]).
// B-tile built by transposing a 64x64 SE/adj tile in LDS during staging.
__global__ __launch_bounds__(256) void node_agg_f(const u16* __restrict__ V1N,
                                                  const u16* __restrict__ SE,
                                                  const float* __restrict__ adj,
                                                  const float* __restrict__ rowsum,
                                                  u16* __restrict__ HB) {
    __shared__ u16 As[64 * 72], Bs[64 * 72];
    int tid = threadIdx.x;
    int w0 = blockIdx.x * 64, bt = blockIdx.y;
    int b = bt / 12, l = bt - b * 12;
    int lane = tid & 63, wid = tid >> 6;
    int wo = (wid & 1) * 32, wm = (wid >> 1) * 32;
    int quad = lane >> 4, r = lane & 15;
    const u16* Ag = V1N + (size_t)bt * 64 * nN;
    int v = tid >> 2, wc = (tid & 3) * 16;
    f32x4 acc[2][2] = {};
    for (int v0 = 0; v0 < nN; v0 += 64) {
        __syncthreads();
        stage64(Ag + v0, nN, As, tid);
        {
            size_t rowg = (size_t)bt * nN + v0 + v;
            float ri = 1.f / rowsum[rowg];
            const u16* se = SE + rowg * nN + w0 + wc;
            const float* ad = adj + rowg * nN + w0 + wc;
            uint4 s0 = *(const uint4*)&se[0], s1 = *(const uint4*)&se[8];
            float4 a0 = *(const float4*)&ad[0], a1 = *(const float4*)&ad[4];
            float4 a2 = *(const float4*)&ad[8], a3 = *(const float4*)&ad[12];
            const u16* sp0 = (const u16*)&s0;
            const u16* sp1 = (const u16*)&s1;
            float av[16] = {a0.x, a0.y, a0.z, a0.w, a1.x, a1.y, a1.z, a1.w,
                            a2.x, a2.y, a2.z, a2.w, a3.x, a3.y, a3.z, a3.w};
#pragma unroll
            for (int ii = 0; ii < 8; ++ii)
                Bs[(wc + ii) * 72 + v] = f2b(b2f(sp0[ii]) * av[ii] * ri);
#pragma unroll
            for (int ii = 0; ii < 8; ++ii)
                Bs[(wc + 8 + ii) * 72 + v] = f2b(b2f(sp1[ii]) * av[8 + ii] * ri);
        }
        __syncthreads();
        mfma_block(As, Bs, acc, wo, wm, quad, r);
    }
#pragma unroll
    for (int oi = 0; oi < 2; ++oi)
#pragma unroll
        for (int mj = 0; mj < 2; ++mj) {
            int c = wo + oi * 16 + quad * 4;
            int w = w0 + wm + mj * 16 + r;
            f32x4 a = acc[oi][mj];
            *(uint2*)&HB[((size_t)b * nM + w * 12 + l) * 128 + 64 + c] =
                packb4(a[0], a[1], a[2], a[3]);
        }
}

// ---------------- time attention (tiny) -------------------------------------
__global__ __launch_bounds__(192) void time_attn(const u16* __restrict__ TQ,
                                                 const u16* __restrict__ TK,
                                                 const float* __restrict__ Bt,
                                                 float* __restrict__ AT) {
    int bn = blockIdx.x;  // b*768 + n
    __shared__ float tqs[nT * 64], tks[nT * 64], ss[nT * nT];
    __shared__ float inv_s[nT], max_s[nT];
    int tid = threadIdx.x;
    size_t base = (size_t)bn * nT * 64;
#pragma unroll
    for (int r = 0; r < 4; ++r) {
        int idx = tid + r * 192;
        tqs[idx] = b2f(TQ[base + idx]);
        tks[idx] = b2f(TK[base + idx]);
    }
    __syncthreads();
    if (tid < 144) {
        int i = tid / 12, j = tid % 12;
        float s = 0.f;
#pragma unroll
        for (int h = 0; h < 64; ++h) s += tqs[i * 64 + h] * tks[j * 64 + h];
        ss[tid] = s * SCALE + Bt[i * 12 + j];
    }
    __syncthreads();
    if (tid < 12) {
        float mx = -1e30f;
        for (int j = 0; j < 12; ++j) mx = fmaxf(mx, ss[tid * 12 + j]);
        float sm = 0.f;
        for (int j = 0; j < 12; ++j) sm += expf(ss[tid * 12 + j] - mx);
        max_s[tid] = mx; inv_s[tid] = 1.f / sm;
    }
    __syncthreads();
    if (tid < 144) {
        int i = tid / 12;
        AT[(size_t)bn * 144 + tid] = expf(ss[tid] - max_s[i]) * inv_s[i];
    }
}

// ---------------- time aggregation ------------------------------------------
__global__ __launch_bounds__(256) void time_agg_k(const u16* __restrict__ V1N,
                                                  const float* __restrict__ AT,
                                                  u16* __restrict__ HB) {
    int tid = threadIdx.x;
    int lane = tid & 63, cg = tid >> 6;
    int n = blockIdx.x * 64 + lane;
    int b = blockIdx.y;
    size_t bn = (size_t)b * nN + n;
#pragma unroll 2
    for (int cc = 0; cc < 16; ++cc) {
        int c = cg * 16 + cc;
        float acc[12] = {};
        for (int v = 0; v < 12; ++v) {
            float val = b2f(V1N[((size_t)(b * 12 + v) * 64 + c) * nN + n]);
            const float4* at4 = (const float4*)(AT + bn * 144 + v * 12);
            float4 a0 = at4[0], a1 = at4[1], a2 = at4[2];
            acc[0] += val * a0.x;  acc[1] += val * a0.y;
            acc[2] += val * a0.z;  acc[3] += val * a0.w;
            acc[4] += val * a1.x;  acc[5] += val * a1.y;
            acc[6] += val * a1.z;  acc[7] += val * a1.w;
            acc[8] += val * a2.x;  acc[9] += val * a2.y;
            acc[10] += val * a2.z; acc[11] += val * a2.w;
        }
#pragma unroll
        for (int t = 0; t < 12; ++t)
            HB[((size_t)b * nM + n * 12 + t) * 128 + c] = f2b(acc[t]);
    }
}

// ---------------------------------------------------------------------------
extern "C" void kernel_launch(void* const* d_in, const int* in_sizes, int n_in,
                              void* d_out, int out_size, void* d_ws, size_t ws_size,
                              hipStream_t stream) {
    const float* x      = (const float*)d_in[0];
    const float* adj    = (const float*)d_in[4];
    const float* ln1w   = (const float*)d_in[5];
    const float* ln1b   = (const float*)d_in[6];
    const float* ln2w   = (const float*)d_in[7];
    const float* ln2b   = (const float*)d_in[8];
    const float* Wnq    = (const float*)d_in[9];
    const float* bnq    = (const float*)d_in[10];
    const float* Wnk    = (const float*)d_in[11];
    const float* bnk    = (const float*)d_in[12];
    const float* Wtq    = (const float*)d_in[13];
    const float* btq    = (const float*)d_in[14];
    const float* Wtk    = (const float*)d_in[15];
    const float* btk    = (const float*)d_in[16];
    const float* Bn     = (const float*)d_in[17];
    const float* Bt     = (const float*)d_in[18];
    const float* v_w    = (const float*)d_in[19];
    const float* v_b    = (const float*)d_in[20];
    const float* fcv_w  = (const float*)d_in[21];
    const float* fcv_b  = (const float*)d_in[22];
    const float* proj_w = (const float*)d_in[23];
    const float* proj_b = (const float*)d_in[24];
    const float* w1     = (const float*)d_in[25];
    const float* b1     = (const float*)d_in[26];
    const float* w2     = (const float*)d_in[27];
    const float* b2     = (const float*)d_in[28];
    float* out = (float*)d_out;

    char* p = (char*)d_ws;
    auto alloc = [&](size_t bytes) { char* q = p; p += (bytes + 255) & ~(size_t)255; return q; };
    u16*   x1cl   = (u16*)alloc(37748736);   // [Mtot][256] bf16
    u16*   nqb    = (u16*)alloc(9437184);    // [bt][n][64] / [m][64]
    u16*   nkb    = (u16*)alloc(9437184);
    u16*   SE     = (u16*)alloc(113246208);  // [bt][v][w] bf16 exp-scores
    float* SC     = (float*)alloc(75497472); // scratch: xr fp32
    u16*   v1n    = (u16*)alloc(9437184);    // [bt][64][n]
    float* atT    = (float*)alloc(3538944);  // [b][n][12][12]
    u16*   hb     = (u16*)alloc(18874368);   // [m][128]
    u16*   vg     = (u16*)alloc(18874368);   // [m][128]
    float* rowsum = (float*)alloc(294912);   // [bt][n]
    u16*   WB     = (u16*)alloc(1081344);    // bf16 weights
    // Aliases (lifetime-checked):
    float* xr   = SC;                          // live prodproj..ffn2
    u16*   x2cl = SE;                          // SE dead after node_agg_f
    u16*   g1   = (u16*)((char*)SE + 37748736);// [Mtot][512] bf16

    dim3 blk(256);
    zero_f<<<dim3(288), blk, 0, stream>>>(rowsum);
    cvt_w<<<dim3(2112), blk, 0, stream>>>(Wnq, Wnk, Wtq, Wtk, v_w, fcv_w, proj_w,
                                          w1, w2, WB);
    ln_cl<<<dim3(144, nB), blk, 0, stream>>>(x, ln1w, ln1b, x1cl);
    // nq+nk in one pass over x1cl
    dual64<0><<<dim3(576, 1), blk, 0, stream>>>(x1cl, WB + 0, WB + 16384,
                                                bnq, bnk, nqb, nkb, 256);
    scores_k<<<dim3(12, 12, nB * nT), blk, 0, stream>>>(nqb, nkb, Bn, SE, rowsum);
    // tq+tk (reuse nqb/nkb)
    dual64<1><<<dim3(576, 1), blk, 0, stream>>>(x1cl, WB + 32768, WB + 49152,
                                                btq, btk, nqb, nkb, 256);
    time_attn<<<dim3(nB * nN), dim3(192), 0, stream>>>(nqb, nkb, Bt, atT);
    gemm_v1<<<dim3(144, nB), blk, 0, stream>>>(x1cl, WB + 65536, v_b, v1n);
    node_agg_f<<<dim3(12, nB * nT), blk, 0, stream>>>(v1n, SE, adj, rowsum, hb);
    time_agg_k<<<dim3(12, nB), blk, 0, stream>>>(v1n, atT, hb);
    // vg = fcv(x1)
    gemm128<0, false><<<dim3(576, 1), blk, 0, stream>>>(WB + 81920, x1cl, nullptr,
                                                        fcv_b, nullptr, vg, 256, 128);
    // xr = proj(h .* vg) + x
    gemm128<1, true><<<dim3(576, 2), blk, 0, stream>>>(WB + 114688, hb, vg,
                                                       proj_b, x, xr, 128, 256);
    ln_cl<<<dim3(144, nB), blk, 0, stream>>>(xr, ln2w, ln2b, x2cl);
    // ffn1 gated
    dual64<2><<<dim3(576, 8), blk, 0, stream>>>(x2cl, WB + 147456, WB + 147456 + 512 * 256,
                                                b1, b1 + 512, g1, nullptr, 256);
    // ffn2 + residual
    gemm128<1, false><<<dim3(576, 2), blk, 0, stream>>>(WB + 409600, g1, nullptr,
                                                        b2, xr, out, 512, 256);
}